// Round 16
// baseline (118.378 us; speedup 1.0000x reference)
//
#include <hip/hip_runtime.h>

// GAT on fully-connected graph, N=4096, F=D=64, H=4, OUT=2.
// 5 fence-free dispatches: encproj | ranks3 | targetproj | ranks3 | target2.
// ranks3 = R14's rank_f (FULL 1024-block parallelism, grid (64,16)) + in-kernel
// handoff: last block per (h,ig) scatters sorted order and bumps done[h];
// the 256 blocks with c16<4 then spin (relaxed, IF$) and run the chunk-local
// suffix/prefix table build (R14 s3off, re-laned to 4 waves x 16 rows).
// __launch_bounds__(256,4) guarantees 4 blocks/CU -> all 1024 co-resident.
// e[t,s,h]=lrelu(dst_t+src_s) factors per branch around -dst.

#define N 4096
#define D 64
#define H 4
#define HD 256
#define TS 66

#define AS(p, v) __hip_atomic_store((p), (v), __ATOMIC_RELAXED, __HIP_MEMORY_SCOPE_AGENT)
#define AL(p)    __hip_atomic_load((p), __ATOMIC_RELAXED, __HIP_MEMORY_SCOPE_AGENT)

__device__ __forceinline__ void fma4(float4& a, float s, const float4& b) {
  a.x = fmaf(s, b.x, a.x); a.y = fmaf(s, b.y, a.y);
  a.z = fmaf(s, b.z, a.z); a.w = fmaf(s, b.w, a.w);
}

// ---- proj: 8 rows from LDS xs, W from global; writes h2, ssrc, sdst ----
__device__ __forceinline__ void proj_dev(const float (*xs)[64], int r0,
    const float* __restrict__ W, const float* __restrict__ asrc,
    const float* __restrict__ adst, float* __restrict__ h2,
    float* __restrict__ ssrc, float* __restrict__ sdst) {
  int tid = threadIdx.x;
  int lane6 = tid & 63;
  int c0 = lane6 * 4;
  int hh = lane6 >> 4;
  int rbase = (tid >> 6) * 2;
  float4 acc0 = make_float4(0.f, 0.f, 0.f, 0.f);
  float4 acc1 = make_float4(0.f, 0.f, 0.f, 0.f);
#pragma unroll
  for (int kq = 0; kq < 16; ++kq) {
    const float* Wk = W + kq * 4 * 256 + c0;
    float4 w0 = *(const float4*)(Wk);
    float4 w1 = *(const float4*)(Wk + 256);
    float4 w2 = *(const float4*)(Wk + 512);
    float4 w3 = *(const float4*)(Wk + 768);
    float4 x0 = *(const float4*)(&xs[rbase][kq * 4]);
    float4 x1 = *(const float4*)(&xs[rbase + 1][kq * 4]);
    fma4(acc0, x0.x, w0); fma4(acc0, x0.y, w1); fma4(acc0, x0.z, w2); fma4(acc0, x0.w, w3);
    fma4(acc1, x1.x, w0); fma4(acc1, x1.y, w1); fma4(acc1, x1.z, w2); fma4(acc1, x1.w, w3);
  }
  float4 av = *(const float4*)(asrc + c0);
  float4 bv = *(const float4*)(adst + c0);
#pragma unroll
  for (int r = 0; r < 2; ++r) {
    float4 a = (r == 0) ? acc0 : acc1;
    int row = r0 + rbase + r;
    *(float4*)(h2 + row * 256 + c0) = a;
    float ps = a.x * av.x + a.y * av.y + a.z * av.z + a.w * av.w;
    float pd = a.x * bv.x + a.y * bv.y + a.z * bv.z + a.w * bv.w;
#pragma unroll
    for (int off = 8; off > 0; off >>= 1) {
      ps += __shfl_down(ps, off);
      pd += __shfl_down(pd, off);
    }
    if ((lane6 & 15) == 0) {
      ssrc[hh * N + row] = ps;
      sdst[hh * N + row] = pd;
    }
  }
}

// ---- layer1: encoder fused with proj; block 0 zeroes sync counters ----
__global__ __launch_bounds__(256) void k_encproj(const float* __restrict__ x,
    const float* __restrict__ Wenc, const float* __restrict__ benc,
    const float* __restrict__ W, const float* __restrict__ asrc,
    const float* __restrict__ adst, float* __restrict__ h2,
    float* __restrict__ ssrc, float* __restrict__ sdst,
    int* __restrict__ sync) {
  __shared__ float xs[8][64];
  int tid = threadIdx.x;
  int r0 = blockIdx.x * 8;
  if (blockIdx.x == 0 && tid < 144) sync[tid] = 0;
  {
    int row = tid >> 5, c = (tid & 31) * 2;
    const float* xr = x + (r0 + row) * 64;
    float a0 = benc[c], a1 = benc[c + 1];
#pragma unroll
    for (int k = 0; k < 64; ++k) {
      float xv = xr[k];
      float2 w = *(const float2*)(Wenc + k * 64 + c);
      a0 = fmaf(xv, w.x, a0);
      a1 = fmaf(xv, w.y, a1);
    }
    xs[row][c] = fmaxf(a0, 0.f);
    xs[row][c + 1] = fmaxf(a1, 0.f);
  }
  __syncthreads();
  proj_dev(xs, r0, W, asrc, adst, h2, ssrc, sdst);
}

// ---- ranks3: rank (full parallelism) + in-kernel handoff to table build ----
// grid (64,16): x = h*16+ig, y = c16. __launch_bounds__(256,4): 4 blocks/CU
// guaranteed -> 1024 blocks co-resident -> relaxed spins are safe.
__global__ __launch_bounds__(256, 4) void k_ranks3(const float* __restrict__ ssrc,
    int* __restrict__ rpart, int* __restrict__ rcnt, int* __restrict__ done,
    float* __restrict__ srtv, int* __restrict__ srti,
    const float* __restrict__ h2,
    float* __restrict__ TA, float* __restrict__ TB, int* __restrict__ scnt,
    float* __restrict__ SA, float* __restrict__ PB,
    float* __restrict__ SufT, float* __restrict__ PreT) {
  __shared__ __align__(16) float vs[256];
  __shared__ int flag;
  __shared__ int pj[64];
  __shared__ float wa[64], wb[64];
  __shared__ float vt[64][66];
  __shared__ float segA[4][66], segB[4][66];
  int h = blockIdx.x >> 4, ig = blockIdx.x & 15, c16 = blockIdx.y;
  int tid = threadIdx.x;

  // ===== Phase R: rank partials (R14 k_rank_f verbatim) =====
  {
    vs[tid] = ssrc[h * N + c16 * 256 + tid];
    __syncthreads();
    int i = ig * 256 + tid;
    float vi = ssrc[h * N + i];
    int jbase = c16 * 256;
    int rank = 0;
    const float4* vs4 = (const float4*)vs;
#pragma unroll 4
    for (int j4 = 0; j4 < 64; ++j4) {
      float4 q = vs4[j4];
      int jb = jbase + (j4 << 2);
      rank += (q.x < vi || (q.x == vi && jb < i));
      rank += (q.y < vi || (q.y == vi && jb + 1 < i));
      rank += (q.z < vi || (q.z == vi && jb + 2 < i));
      rank += (q.w < vi || (q.w == vi && jb + 3 < i));
    }
    AS(&rpart[(c16 * H + h) * N + i], rank);
    asm volatile("s_waitcnt vmcnt(0)" ::: "memory");
    __syncthreads();
    if (tid == 0) {
      int prev = __hip_atomic_fetch_add(&rcnt[h * 16 + ig], 1,
                   __ATOMIC_RELAXED, __HIP_MEMORY_SCOPE_AGENT);
      flag = (prev == 15);
    }
    __syncthreads();
    if (flag) {
      int rk = 0;
#pragma unroll
      for (int cc = 0; cc < 16; ++cc) rk += AL(&rpart[(cc * H + h) * N + i]);
      AS(&srtv[h * N + rk], vi);
      AS(&srti[h * N + rk], i);
      asm volatile("s_waitcnt vmcnt(0)" ::: "memory");
      __syncthreads();
      if (tid == 0)
        __hip_atomic_fetch_add(&done[h], 1, __ATOMIC_RELAXED, __HIP_MEMORY_SCOPE_AGENT);
    }
  }

  // ===== Phase S3: only blocks with c16 < 4 continue (256 blocks) =====
  if (c16 >= 4) return;
  int c = ig * 4 + c16;
  int w = tid >> 6, lane = tid & 63;   // 4 waves x 16 rows
  int j0 = c * 64;
  if (tid == 0) {
    while (AL(&done[h]) < 16) __builtin_amdgcn_s_sleep(2);
  }
  __syncthreads();
  if (tid < 64) {
    int j = j0 + tid;
    pj[tid] = AL(&srti[h * N + j]);
    float sv = AL(&srtv[h * N + j]);
    float m1 = AL(&srtv[h * N + N - 1]);
    wa[tid] = expf(sv - m1);
    wb[tid] = expf(0.2f * (sv - m1));
  }
  __syncthreads();
#pragma unroll
  for (int jj = 0; jj < 16; ++jj) {
    int j = jj * 4 + w;
    vt[j][lane] = h2[pj[j] * HD + h * 64 + lane];
  }
  __syncthreads();
  {
    float sA = 0.f, sB = 0.f;
#pragma unroll
    for (int jj = 0; jj < 16; ++jj) {
      int j = w * 16 + jj;
      float v = vt[j][lane];
      sA = fmaf(wa[j], v, sA);
      sB = fmaf(wb[j], v, sB);
    }
    segA[w][lane] = sA; segB[w][lane] = sB;
    if (lane == 0) {
      float swA = 0.f, swB = 0.f;
#pragma unroll
      for (int jj = 0; jj < 16; ++jj) { swA += wa[w * 16 + jj]; swB += wb[w * 16 + jj]; }
      segA[w][64] = swA; segB[w][64] = swB;
    }
  }
  __syncthreads();
  size_t base = (size_t)h * (N + 1);
  {
    float acc = 0.f;
    for (int w2 = w + 1; w2 < 4; ++w2) acc += segA[w2][lane];
#pragma unroll
    for (int jj = 15; jj >= 0; --jj) {
      int j = w * 16 + jj;
      acc = fmaf(wa[j], vt[j][lane], acc);
      SA[(base + j0 + j) * TS + lane] = acc;
    }
  }
  {
    float acc = 0.f;
    for (int w2 = 0; w2 < w; ++w2) acc += segB[w2][lane];
#pragma unroll
    for (int jj = 0; jj < 16; ++jj) {
      int j = w * 16 + jj;
      PB[(base + j0 + j) * TS + lane] = acc;
      acc = fmaf(wb[j], vt[j][lane], acc);
    }
  }
  if (lane == 0) {
    float a = 0.f;
    for (int w2 = w + 1; w2 < 4; ++w2) a += segA[w2][64];
#pragma unroll
    for (int jj = 15; jj >= 0; --jj) {
      int j = w * 16 + jj;
      a += wa[j];
      SA[(base + j0 + j) * TS + 64] = a;
    }
  }
  if (lane == 1) {
    float bsum = 0.f;
    for (int w2 = 0; w2 < w; ++w2) bsum += segB[w2][64];
#pragma unroll
    for (int jj = 0; jj < 16; ++jj) {
      int j = w * 16 + jj;
      PB[(base + j0 + j) * TS + 64] = bsum;
      bsum += wb[j];
    }
  }
  if (tid < 65) {
    float tA = 0.f, tB = 0.f;
#pragma unroll
    for (int w2 = 0; w2 < 4; ++w2) { tA += segA[w2][tid]; tB += segB[w2][tid]; }
    AS(&TA[(h * 64 + c) * TS + tid], tA);
    AS(&TB[(h * 64 + c) * TS + tid], tB);
  }
  asm volatile("s_waitcnt vmcnt(0)" ::: "memory");
  __syncthreads();
  if (tid == 0) {
    int prev = __hip_atomic_fetch_add(&scnt[h], 1,
                 __ATOMIC_RELAXED, __HIP_MEMORY_SCOPE_AGENT);
    flag = (prev == 63);
  }
  __syncthreads();
  if (!flag) return;
  // parallel SufT/PreT build (LDS-staged), 256 threads
  __syncthreads();
#pragma unroll
  for (int it = 0; it < 17; ++it) {
    int idx = it * 256 + tid;
    if (idx < 64 * 65) {
      int cc = idx / 65, col = idx - cc * 65;
      vt[cc][col] = AL(&TA[(h * 64 + cc) * TS + col]);
    }
  }
  __syncthreads();
  if (tid < 65) {
    float acc = 0.f;
    SufT[(h * 65 + 64) * TS + tid] = 0.f;
    for (int cc = 63; cc >= 0; --cc) {
      SufT[(h * 65 + cc) * TS + tid] = acc;
      acc += vt[cc][tid];
    }
  }
  __syncthreads();
#pragma unroll
  for (int it = 0; it < 17; ++it) {
    int idx = it * 256 + tid;
    if (idx < 64 * 65) {
      int cc = idx / 65, col = idx - cc * 65;
      vt[cc][col] = AL(&TB[(h * 64 + cc) * TS + col]);
    }
  }
  __syncthreads();
  if (tid < 65) {
    float acc = 0.f;
    for (int cc = 0; cc < 64; ++cc) {
      PreT[(h * 65 + cc) * TS + tid] = acc;
      acc += vt[cc][tid];
    }
    PreT[(h * 65 + 64) * TS + tid] = acc;
    SA[(base + N) * TS + tid] = 0.f;
    PB[(base + N) * TS + tid] = 0.f;
  }
}

// ---- target core: rows t0 + tid>>6 + 4*task; local tables + Suf/Pre ----
template <int MODE>
__device__ __forceinline__ void target_dev(int t0, int tid,
    const float* __restrict__ sdst, const float* __restrict__ srtv,
    const float* __restrict__ SA, const float* __restrict__ PB,
    const float* __restrict__ SufT, const float* __restrict__ PreT,
    const float* __restrict__ bias, float (*xsout)[64], const float (*bnd)[64],
    const float* __restrict__ Wact, const float* __restrict__ bact,
    const float* __restrict__ Wcri, const float* __restrict__ bcri,
    float* __restrict__ out, int ntask) {
  int lane = tid & 63;
  for (int task = 0; task < ntask; ++task) {
    int r = task * 4 + (tid >> 6);
    int t = t0 + r;
    float acc = 0.f;
#pragma unroll
    for (int h = 0; h < H; ++h) {
      const float* sv = srtv + h * N;
      float dst = sdst[h * N + t];
      float thr = -dst;
      float m1 = sv[N - 1];
      unsigned long long b1m = __ballot(bnd[h][lane] <= thr);
      int c1 = __popcll(b1m);
      int seg = c1 > 0 ? c1 - 1 : 0;
      unsigned long long b2m = __ballot(sv[seg * 64 + lane] <= thr);
      int k = seg * 64 + __popcll(b2m);
      int c = k >> 6;
      float u = dst + m1;
      float g = fmaxf(u, 0.2f * u);
      float wAt = expf(u - g);
      float wBt = expf(0.2f * u - g);
      const float* sa = SA + (size_t)(h * (N + 1) + k) * TS;
      const float* pb = PB + (size_t)(h * (N + 1) + k) * TS;
      const float* sf = SufT + (size_t)(h * 65 + c) * TS;
      const float* pr = PreT + (size_t)(h * 65 + c) * TS;
      float num = wAt * (sa[lane] + sf[lane]) + wBt * (pb[lane] + pr[lane]);
      float den = wAt * (sa[64] + sf[64]) + wBt * (pb[64] + pr[64]);
      acc += num / den;
    }
    float hv = fmaxf(acc * 0.25f + bias[lane], 0.f);
    if constexpr (MODE == 0) {
      xsout[r][lane] = hv;
    } else {
      float p0 = hv * Wact[lane * 2 + 0];
      float p1 = hv * Wact[lane * 2 + 1];
      float p2 = hv * Wcri[lane];
#pragma unroll
      for (int off = 32; off > 0; off >>= 1) {
        p0 += __shfl_down(p0, off);
        p1 += __shfl_down(p1, off);
        p2 += __shfl_down(p2, off);
      }
      if (lane == 0) {
        float l0 = fminf(fmaxf(p0 + bact[0], -5.f), 5.f);
        float l1 = fminf(fmaxf(p1 + bact[1], -5.f), 5.f);
        out[t * 2 + 0] = l0;
        out[t * 2 + 1] = fabsf(l1);
        out[2 * N + t] = p2 + bcri[0];
      }
    }
  }
}

// ---- target1 (8 rows -> LDS) fused with proj2 ----
__global__ __launch_bounds__(256) void k_targetproj(
    const float* __restrict__ sdst, const float* __restrict__ srtv,
    const float* __restrict__ SA, const float* __restrict__ PB,
    const float* __restrict__ SufT, const float* __restrict__ PreT,
    const float* __restrict__ bias,
    const float* __restrict__ W, const float* __restrict__ asrc,
    const float* __restrict__ adst, float* __restrict__ h2,
    float* __restrict__ ssrc2, float* __restrict__ sdst2) {
  __shared__ float xs[8][64];
  __shared__ float bnd[4][64];
  int tid = threadIdx.x;
  int r0 = blockIdx.x * 8;
  { int hh = tid >> 6, l = tid & 63; bnd[hh][l] = srtv[hh * N + l * 64]; }
  __syncthreads();
  target_dev<0>(r0, tid, sdst, srtv, SA, PB, SufT, PreT, bias, xs, bnd,
                nullptr, nullptr, nullptr, nullptr, nullptr, 2);
  __syncthreads();
  proj_dev(xs, r0, W, asrc, adst, h2, ssrc2, sdst2);
}

// ---- target2 + heads ----
__global__ __launch_bounds__(256) void k_target2(
    const float* __restrict__ sdst, const float* __restrict__ srtv,
    const float* __restrict__ SA, const float* __restrict__ PB,
    const float* __restrict__ SufT, const float* __restrict__ PreT,
    const float* __restrict__ bias,
    const float* __restrict__ Wact, const float* __restrict__ bact,
    const float* __restrict__ Wcri, const float* __restrict__ bcri,
    float* __restrict__ out) {
  __shared__ float bnd[4][64];
  int tid = threadIdx.x;
  { int hh = tid >> 6, l = tid & 63; bnd[hh][l] = srtv[hh * N + l * 64]; }
  __syncthreads();
  target_dev<1>(blockIdx.x * 4, tid, sdst, srtv, SA, PB, SufT, PreT, bias,
                nullptr, bnd, Wact, bact, Wcri, bcri, out, 1);
}

extern "C" void kernel_launch(void* const* d_in, const int* in_sizes, int n_in,
                              void* d_out, int out_size, void* d_ws, size_t ws_size,
                              hipStream_t stream) {
    (void)in_sizes; (void)n_in; (void)out_size; (void)ws_size;
    const float* x     = (const float*)d_in[0];
    const float* W_enc = (const float*)d_in[1];
    const float* b_enc = (const float*)d_in[2];
    const float* W1    = (const float*)d_in[3];
    const float* as1   = (const float*)d_in[4];
    const float* ad1   = (const float*)d_in[5];
    const float* b1    = (const float*)d_in[6];
    const float* W2    = (const float*)d_in[7];
    const float* as2   = (const float*)d_in[8];
    const float* ad2   = (const float*)d_in[9];
    const float* b2    = (const float*)d_in[10];
    const float* W_act = (const float*)d_in[11];
    const float* b_act = (const float*)d_in[12];
    const float* W_cri = (const float*)d_in[13];
    const float* b_cri = (const float*)d_in[14];
    float* out = (float*)d_out;

    float* p = (float*)d_ws;
    float* h2    = p; p += N * HD;
    float* ssrc1 = p; p += H * N;
    float* sdst1 = p; p += H * N;
    float* ssrc2 = p; p += H * N;
    float* sdst2 = p; p += H * N;
    float* srtv  = p; p += H * N;
    int*   srti  = (int*)p; p += H * N;
    float* TA    = p; p += H * 64 * TS;
    float* TB    = p; p += H * 64 * TS;
    float* SufT  = p; p += H * 65 * TS;
    float* PreT  = p; p += H * 65 * TS;
    float* SA    = p; p += (size_t)H * (N + 1) * TS;
    float* PB    = p; p += (size_t)H * (N + 1) * TS;
    int*   rpart = (int*)p; p += 16 * H * N;
    int*   sync  = (int*)p; p += 256;
    // layer1: [0:64) rcnt1, [64:68) done1, [68:72) scnt1
    // layer2: [72:136) rcnt2, [136:140) done2, [140:144) scnt2

    int* rcnt1 = sync;
    int* done1 = sync + 64;
    int* scnt1 = sync + 68;
    int* rcnt2 = sync + 72;
    int* done2 = sync + 136;
    int* scnt2 = sync + 140;

    dim3 rgrid(64, 16);

    // layer 1
    k_encproj<<<N / 8, 256, 0, stream>>>(x, W_enc, b_enc, W1, as1, ad1,
                                         h2, ssrc1, sdst1, sync);
    k_ranks3<<<rgrid, 256, 0, stream>>>(ssrc1, rpart, rcnt1, done1, srtv, srti,
                                        h2, TA, TB, scnt1, SA, PB, SufT, PreT);
    k_targetproj<<<N / 8, 256, 0, stream>>>(sdst1, srtv, SA, PB, SufT, PreT, b1,
                                            W2, as2, ad2, h2, ssrc2, sdst2);
    // layer 2
    k_ranks3<<<rgrid, 256, 0, stream>>>(ssrc2, rpart, rcnt2, done2, srtv, srti,
                                        h2, TA, TB, scnt2, SA, PB, SufT, PreT);
    k_target2<<<N / 4, 256, 0, stream>>>(sdst2, srtv, SA, PB, SufT, PreT, b2,
                                         W_act, b_act, W_cri, b_cri, out);
}

// Round 17
// 100.967 us; speedup vs baseline: 1.1724x; 1.1724x over previous
//
#include <hip/hip_runtime.h>

// GAT on fully-connected graph, N=4096, F=D=64, H=4, OUT=2.
// 7 fence-free dispatches (R14 structure = structural optimum; merges tested
// in R15/R16 both regressed): encproj | rankF | s3off | targetproj | rankF |
// s3off | target2.  Micro-opts this round: coalesced LDS staging of x in
// encproj; per-layer bndG boundary array precomputed in s3off tail (kills
// the stride-256B srtv scatter in every target block).
// e[t,s,h]=lrelu(dst_t+src_s) factors per branch around -dst.

#define N 4096
#define D 64
#define H 4
#define HD 256
#define TS 66

#define AS(p, v) __hip_atomic_store((p), (v), __ATOMIC_RELAXED, __HIP_MEMORY_SCOPE_AGENT)
#define AL(p)    __hip_atomic_load((p), __ATOMIC_RELAXED, __HIP_MEMORY_SCOPE_AGENT)

__device__ __forceinline__ void fma4(float4& a, float s, const float4& b) {
  a.x = fmaf(s, b.x, a.x); a.y = fmaf(s, b.y, a.y);
  a.z = fmaf(s, b.z, a.z); a.w = fmaf(s, b.w, a.w);
}

// ---- proj: 8 rows from LDS xs, W from global; writes h2, ssrc, sdst ----
__device__ __forceinline__ void proj_dev(const float (*xs)[64], int r0,
    const float* __restrict__ W, const float* __restrict__ asrc,
    const float* __restrict__ adst, float* __restrict__ h2,
    float* __restrict__ ssrc, float* __restrict__ sdst) {
  int tid = threadIdx.x;
  int lane6 = tid & 63;
  int c0 = lane6 * 4;
  int hh = lane6 >> 4;
  int rbase = (tid >> 6) * 2;
  float4 acc0 = make_float4(0.f, 0.f, 0.f, 0.f);
  float4 acc1 = make_float4(0.f, 0.f, 0.f, 0.f);
#pragma unroll
  for (int kq = 0; kq < 16; ++kq) {
    const float* Wk = W + kq * 4 * 256 + c0;
    float4 w0 = *(const float4*)(Wk);
    float4 w1 = *(const float4*)(Wk + 256);
    float4 w2 = *(const float4*)(Wk + 512);
    float4 w3 = *(const float4*)(Wk + 768);
    float4 x0 = *(const float4*)(&xs[rbase][kq * 4]);
    float4 x1 = *(const float4*)(&xs[rbase + 1][kq * 4]);
    fma4(acc0, x0.x, w0); fma4(acc0, x0.y, w1); fma4(acc0, x0.z, w2); fma4(acc0, x0.w, w3);
    fma4(acc1, x1.x, w0); fma4(acc1, x1.y, w1); fma4(acc1, x1.z, w2); fma4(acc1, x1.w, w3);
  }
  float4 av = *(const float4*)(asrc + c0);
  float4 bv = *(const float4*)(adst + c0);
#pragma unroll
  for (int r = 0; r < 2; ++r) {
    float4 a = (r == 0) ? acc0 : acc1;
    int row = r0 + rbase + r;
    *(float4*)(h2 + row * 256 + c0) = a;
    float ps = a.x * av.x + a.y * av.y + a.z * av.z + a.w * av.w;
    float pd = a.x * bv.x + a.y * bv.y + a.z * bv.z + a.w * bv.w;
#pragma unroll
    for (int off = 8; off > 0; off >>= 1) {
      ps += __shfl_down(ps, off);
      pd += __shfl_down(pd, off);
    }
    if ((lane6 & 15) == 0) {
      ssrc[hh * N + row] = ps;
      sdst[hh * N + row] = pd;
    }
  }
}

// ---- layer1: encoder fused with proj; x staged via coalesced float4 ----
__global__ __launch_bounds__(256) void k_encproj(const float* __restrict__ x,
    const float* __restrict__ Wenc, const float* __restrict__ benc,
    const float* __restrict__ W, const float* __restrict__ asrc,
    const float* __restrict__ adst, float* __restrict__ h2,
    float* __restrict__ ssrc, float* __restrict__ sdst,
    int* __restrict__ sync) {
  __shared__ float xin[8][64];
  __shared__ float xs[8][64];
  int tid = threadIdx.x;
  int r0 = blockIdx.x * 8;
  if (blockIdx.x == 0 && tid < 136) sync[tid] = 0;
  if (tid < 128) ((float4*)xin)[tid] = ((const float4*)(x + r0 * 64))[tid];
  __syncthreads();
  {
    int row = tid >> 5, c = (tid & 31) * 2;
    float a0 = benc[c], a1 = benc[c + 1];
#pragma unroll
    for (int k = 0; k < 64; ++k) {
      float xv = xin[row][k];
      float2 w = *(const float2*)(Wenc + k * 64 + c);
      a0 = fmaf(xv, w.x, a0);
      a1 = fmaf(xv, w.y, a1);
    }
    xs[row][c] = fmaxf(a0, 0.f);
    xs[row][c + 1] = fmaxf(a1, 0.f);
  }
  __syncthreads();
  proj_dev(xs, r0, W, asrc, adst, h2, ssrc, sdst);
}

// ---- rank fused: partial counts via IF$ atomics; last block reduces ----
__global__ __launch_bounds__(256) void k_rank_f(const float* __restrict__ ssrc,
    int* __restrict__ rpart, int* __restrict__ cnt,
    float* __restrict__ srtv, int* __restrict__ srti) {
  __shared__ __align__(16) float vs[256];
  __shared__ int lastflag;
  int h = blockIdx.x >> 4, ig = blockIdx.x & 15, c = blockIdx.y;
  int tid = threadIdx.x;
  vs[tid] = ssrc[h * N + c * 256 + tid];
  __syncthreads();
  int i = ig * 256 + tid;
  float vi = ssrc[h * N + i];
  int jbase = c * 256;
  int rank = 0;
  const float4* vs4 = (const float4*)vs;
#pragma unroll 4
  for (int j4 = 0; j4 < 64; ++j4) {
    float4 q = vs4[j4];
    int jb = jbase + (j4 << 2);
    rank += (q.x < vi || (q.x == vi && jb < i));
    rank += (q.y < vi || (q.y == vi && jb + 1 < i));
    rank += (q.z < vi || (q.z == vi && jb + 2 < i));
    rank += (q.w < vi || (q.w == vi && jb + 3 < i));
  }
  AS(&rpart[(c * H + h) * N + i], rank);
  asm volatile("s_waitcnt vmcnt(0)" ::: "memory");
  __syncthreads();
  if (tid == 0) {
    int prev = __hip_atomic_fetch_add(&cnt[h * 16 + ig], 1,
                 __ATOMIC_RELAXED, __HIP_MEMORY_SCOPE_AGENT);
    lastflag = (prev == 15);
  }
  __syncthreads();
  if (lastflag) {
    int rk = 0;
#pragma unroll
    for (int cc = 0; cc < 16; ++cc) rk += AL(&rpart[(cc * H + h) * N + i]);
    srtv[h * N + rk] = vi;
    srti[h * N + rk] = i;
  }
}

// ---- s3off: chunk-LOCAL suffix/prefix tables + totals; last block/head
//      builds SufT/PreT (parallel LDS-staged) + bndG boundary array. ----
// grid 256 (h*64+c), block 512 (8 waves, 8 rows each).
__global__ __launch_bounds__(512) void k_s3off(const float* __restrict__ h2,
    const int* __restrict__ srti, const float* __restrict__ srtv,
    float* __restrict__ TA, float* __restrict__ TB, int* __restrict__ cnt,
    float* __restrict__ SA, float* __restrict__ PB,
    float* __restrict__ SufT, float* __restrict__ PreT,
    float* __restrict__ bndG) {
  __shared__ int pj[64];
  __shared__ float wa[64], wb[64];
  __shared__ float vt[64][66];
  __shared__ float segA[8][66], segB[8][66];
  __shared__ int lastflag;
  int h = blockIdx.x >> 6, c = blockIdx.x & 63;
  int tid = threadIdx.x, w = tid >> 6, lane = tid & 63;
  int j0 = c * 64;
  if (tid < 64) {
    int j = j0 + tid;
    pj[tid] = srti[h * N + j];
    float sv = srtv[h * N + j];
    float m1 = srtv[h * N + N - 1];
    wa[tid] = expf(sv - m1);
    wb[tid] = expf(0.2f * (sv - m1));
  }
  __syncthreads();
  // gather 64 rows, 8 per wave
#pragma unroll
  for (int jj = 0; jj < 8; ++jj) {
    int j = jj * 8 + w;
    vt[j][lane] = h2[pj[j] * HD + h * 64 + lane];
  }
  __syncthreads();
  // per-wave segment sums over rows [w*8, w*8+8)
  {
    float sA = 0.f, sB = 0.f;
#pragma unroll
    for (int jj = 0; jj < 8; ++jj) {
      int j = w * 8 + jj;
      float v = vt[j][lane];
      sA = fmaf(wa[j], v, sA);
      sB = fmaf(wb[j], v, sB);
    }
    segA[w][lane] = sA; segB[w][lane] = sB;
    if (lane == 0) {
      float swA = 0.f, swB = 0.f;
#pragma unroll
      for (int jj = 0; jj < 8; ++jj) { swA += wa[w * 8 + jj]; swB += wb[w * 8 + jj]; }
      segA[w][64] = swA; segB[w][64] = swB;
    }
  }
  __syncthreads();
  size_t base = (size_t)h * (N + 1);
  // local suffix chain (cols 0..63)
  {
    float acc = 0.f;
    for (int w2 = w + 1; w2 < 8; ++w2) acc += segA[w2][lane];
#pragma unroll
    for (int jj = 7; jj >= 0; --jj) {
      int j = w * 8 + jj;
      acc = fmaf(wa[j], vt[j][lane], acc);
      SA[(base + j0 + j) * TS + lane] = acc;
    }
  }
  // local prefix chain (cols 0..63)
  {
    float acc = 0.f;
    for (int w2 = 0; w2 < w; ++w2) acc += segB[w2][lane];
#pragma unroll
    for (int jj = 0; jj < 8; ++jj) {
      int j = w * 8 + jj;
      PB[(base + j0 + j) * TS + lane] = acc;
      acc = fmaf(wb[j], vt[j][lane], acc);
    }
  }
  // col-64 (weight-sum) chains: lane0 -> SA, lane1 -> PB
  if (lane == 0) {
    float a = 0.f;
    for (int w2 = w + 1; w2 < 8; ++w2) a += segA[w2][64];
#pragma unroll
    for (int jj = 7; jj >= 0; --jj) {
      int j = w * 8 + jj;
      a += wa[j];
      SA[(base + j0 + j) * TS + 64] = a;
    }
  }
  if (lane == 1) {
    float bsum = 0.f;
    for (int w2 = 0; w2 < w; ++w2) bsum += segB[w2][64];
#pragma unroll
    for (int jj = 0; jj < 8; ++jj) {
      int j = w * 8 + jj;
      PB[(base + j0 + j) * TS + 64] = bsum;
      bsum += wb[j];
    }
  }
  // publish chunk totals (IF$-coherent)
  if (tid < 65) {
    float tA = 0.f, tB = 0.f;
#pragma unroll
    for (int w2 = 0; w2 < 8; ++w2) { tA += segA[w2][tid]; tB += segB[w2][tid]; }
    AS(&TA[(h * 64 + c) * TS + tid], tA);
    AS(&TB[(h * 64 + c) * TS + tid], tB);
  }
  asm volatile("s_waitcnt vmcnt(0)" ::: "memory");
  __syncthreads();
  if (tid == 0) {
    int prev = __hip_atomic_fetch_add(&cnt[h], 1,
                 __ATOMIC_RELAXED, __HIP_MEMORY_SCOPE_AGENT);
    lastflag = (prev == 63);
  }
  __syncthreads();
  if (!lastflag) return;
  // ---- PARALLEL SufT/PreT build + bndG ----
  __syncthreads();
  if (tid < 64) bndG[h * 64 + tid] = srtv[h * N + tid * 64];
#pragma unroll
  for (int it = 0; it < 9; ++it) {
    int idx = it * 512 + tid;
    if (idx < 64 * 65) {
      int cc = idx / 65, col = idx - cc * 65;
      vt[cc][col] = AL(&TA[(h * 64 + cc) * TS + col]);
    }
  }
  __syncthreads();
  if (tid < 65) {
    float acc = 0.f;
    SufT[(h * 65 + 64) * TS + tid] = 0.f;
    for (int cc = 63; cc >= 0; --cc) {
      SufT[(h * 65 + cc) * TS + tid] = acc;        // sum_{c'>cc}
      acc += vt[cc][tid];
    }
  }
  __syncthreads();
#pragma unroll
  for (int it = 0; it < 9; ++it) {
    int idx = it * 512 + tid;
    if (idx < 64 * 65) {
      int cc = idx / 65, col = idx - cc * 65;
      vt[cc][col] = AL(&TB[(h * 64 + cc) * TS + col]);
    }
  }
  __syncthreads();
  if (tid < 65) {
    float acc = 0.f;
    for (int cc = 0; cc < 64; ++cc) {
      PreT[(h * 65 + cc) * TS + tid] = acc;        // sum_{c'<cc}
      acc += vt[cc][tid];
    }
    PreT[(h * 65 + 64) * TS + tid] = acc;
    SA[(base + N) * TS + tid] = 0.f;
    PB[(base + N) * TS + tid] = 0.f;
  }
}

// ---- target core: rows t0 + tid>>6 + 4*task; local tables + Suf/Pre ----
template <int MODE>
__device__ __forceinline__ void target_dev(int t0, int tid,
    const float* __restrict__ sdst, const float* __restrict__ srtv,
    const float* __restrict__ SA, const float* __restrict__ PB,
    const float* __restrict__ SufT, const float* __restrict__ PreT,
    const float* __restrict__ bias, float (*xsout)[64], const float (*bnd)[64],
    const float* __restrict__ Wact, const float* __restrict__ bact,
    const float* __restrict__ Wcri, const float* __restrict__ bcri,
    float* __restrict__ out, int ntask) {
  int lane = tid & 63;
  for (int task = 0; task < ntask; ++task) {
    int r = task * 4 + (tid >> 6);
    int t = t0 + r;
    float acc = 0.f;
#pragma unroll
    for (int h = 0; h < H; ++h) {
      const float* sv = srtv + h * N;
      float dst = sdst[h * N + t];
      float thr = -dst;
      float m1 = sv[N - 1];
      unsigned long long b1m = __ballot(bnd[h][lane] <= thr);
      int c1 = __popcll(b1m);
      int seg = c1 > 0 ? c1 - 1 : 0;
      unsigned long long b2m = __ballot(sv[seg * 64 + lane] <= thr);
      int k = seg * 64 + __popcll(b2m);
      int c = k >> 6;
      float u = dst + m1;
      float g = fmaxf(u, 0.2f * u);
      float wAt = expf(u - g);
      float wBt = expf(0.2f * u - g);
      const float* sa = SA + (size_t)(h * (N + 1) + k) * TS;
      const float* pb = PB + (size_t)(h * (N + 1) + k) * TS;
      const float* sf = SufT + (size_t)(h * 65 + c) * TS;
      const float* pr = PreT + (size_t)(h * 65 + c) * TS;
      float num = wAt * (sa[lane] + sf[lane]) + wBt * (pb[lane] + pr[lane]);
      float den = wAt * (sa[64] + sf[64]) + wBt * (pb[64] + pr[64]);
      acc += num / den;
    }
    float hv = fmaxf(acc * 0.25f + bias[lane], 0.f);
    if constexpr (MODE == 0) {
      xsout[r][lane] = hv;
    } else {
      float p0 = hv * Wact[lane * 2 + 0];
      float p1 = hv * Wact[lane * 2 + 1];
      float p2 = hv * Wcri[lane];
#pragma unroll
      for (int off = 32; off > 0; off >>= 1) {
        p0 += __shfl_down(p0, off);
        p1 += __shfl_down(p1, off);
        p2 += __shfl_down(p2, off);
      }
      if (lane == 0) {
        float l0 = fminf(fmaxf(p0 + bact[0], -5.f), 5.f);
        float l1 = fminf(fmaxf(p1 + bact[1], -5.f), 5.f);
        out[t * 2 + 0] = l0;
        out[t * 2 + 1] = fabsf(l1);
        out[2 * N + t] = p2 + bcri[0];
      }
    }
  }
}

// ---- target1 (8 rows -> LDS) fused with proj2 ----
__global__ __launch_bounds__(256) void k_targetproj(
    const float* __restrict__ sdst, const float* __restrict__ srtv,
    const float* __restrict__ SA, const float* __restrict__ PB,
    const float* __restrict__ SufT, const float* __restrict__ PreT,
    const float* __restrict__ bndG, const float* __restrict__ bias,
    const float* __restrict__ W, const float* __restrict__ asrc,
    const float* __restrict__ adst, float* __restrict__ h2,
    float* __restrict__ ssrc2, float* __restrict__ sdst2) {
  __shared__ float xs[8][64];
  __shared__ float bnd[4][64];
  int tid = threadIdx.x;
  int r0 = blockIdx.x * 8;
  if (tid < 256) ((float*)bnd)[tid] = bndG[tid];
  __syncthreads();
  target_dev<0>(r0, tid, sdst, srtv, SA, PB, SufT, PreT, bias, xs, bnd,
                nullptr, nullptr, nullptr, nullptr, nullptr, 2);
  __syncthreads();
  proj_dev(xs, r0, W, asrc, adst, h2, ssrc2, sdst2);
}

// ---- target2 + heads ----
__global__ __launch_bounds__(256) void k_target2(
    const float* __restrict__ sdst, const float* __restrict__ srtv,
    const float* __restrict__ SA, const float* __restrict__ PB,
    const float* __restrict__ SufT, const float* __restrict__ PreT,
    const float* __restrict__ bndG, const float* __restrict__ bias,
    const float* __restrict__ Wact, const float* __restrict__ bact,
    const float* __restrict__ Wcri, const float* __restrict__ bcri,
    float* __restrict__ out) {
  __shared__ float bnd[4][64];
  int tid = threadIdx.x;
  if (tid < 256) ((float*)bnd)[tid] = bndG[tid];
  __syncthreads();
  target_dev<1>(blockIdx.x * 4, tid, sdst, srtv, SA, PB, SufT, PreT, bias,
                nullptr, bnd, Wact, bact, Wcri, bcri, out, 1);
}

extern "C" void kernel_launch(void* const* d_in, const int* in_sizes, int n_in,
                              void* d_out, int out_size, void* d_ws, size_t ws_size,
                              hipStream_t stream) {
    (void)in_sizes; (void)n_in; (void)out_size; (void)ws_size;
    const float* x     = (const float*)d_in[0];
    const float* W_enc = (const float*)d_in[1];
    const float* b_enc = (const float*)d_in[2];
    const float* W1    = (const float*)d_in[3];
    const float* as1   = (const float*)d_in[4];
    const float* ad1   = (const float*)d_in[5];
    const float* b1    = (const float*)d_in[6];
    const float* W2    = (const float*)d_in[7];
    const float* as2   = (const float*)d_in[8];
    const float* ad2   = (const float*)d_in[9];
    const float* b2    = (const float*)d_in[10];
    const float* W_act = (const float*)d_in[11];
    const float* b_act = (const float*)d_in[12];
    const float* W_cri = (const float*)d_in[13];
    const float* b_cri = (const float*)d_in[14];
    float* out = (float*)d_out;

    float* p = (float*)d_ws;
    float* h2    = p; p += N * HD;
    float* ssrc1 = p; p += H * N;
    float* sdst1 = p; p += H * N;
    float* ssrc2 = p; p += H * N;
    float* sdst2 = p; p += H * N;
    float* srtv  = p; p += H * N;
    int*   srti  = (int*)p; p += H * N;
    float* TA    = p; p += H * 64 * TS;
    float* TB    = p; p += H * 64 * TS;
    float* SufT  = p; p += H * 65 * TS;
    float* PreT  = p; p += H * 65 * TS;
    float* bndG  = p; p += H * 64;
    float* SA    = p; p += (size_t)H * (N + 1) * TS;
    float* PB    = p; p += (size_t)H * (N + 1) * TS;
    int*   rpart = (int*)p; p += 16 * H * N;
    int*   sync  = (int*)p; p += 256;

    int* rcnt1 = sync;
    int* scnt1 = sync + 64;
    int* rcnt2 = sync + 68;
    int* scnt2 = sync + 132;

    dim3 rgrid(64, 16);

    // layer 1
    k_encproj<<<N / 8, 256, 0, stream>>>(x, W_enc, b_enc, W1, as1, ad1,
                                         h2, ssrc1, sdst1, sync);
    k_rank_f<<<rgrid, 256, 0, stream>>>(ssrc1, rpart, rcnt1, srtv, srti);
    k_s3off<<<256, 512, 0, stream>>>(h2, srti, srtv, TA, TB, scnt1, SA, PB,
                                     SufT, PreT, bndG);
    k_targetproj<<<N / 8, 256, 0, stream>>>(sdst1, srtv, SA, PB, SufT, PreT,
                                            bndG, b1, W2, as2, ad2, h2, ssrc2, sdst2);
    // layer 2
    k_rank_f<<<rgrid, 256, 0, stream>>>(ssrc2, rpart, rcnt2, srtv, srti);
    k_s3off<<<256, 512, 0, stream>>>(h2, srti, srtv, TA, TB, scnt2, SA, PB,
                                     SufT, PreT, bndG);
    k_target2<<<N / 4, 256, 0, stream>>>(sdst2, srtv, SA, PB, SufT, PreT,
                                         bndG, b2, W_act, b_act, W_cri, b_cri, out);
}

// Round 18
// 98.131 us; speedup vs baseline: 1.2063x; 1.0289x over previous
//
#include <hip/hip_runtime.h>

// GAT on fully-connected graph, N=4096, F=D=64, H=4, OUT=2.
// 7 fence-free dispatches (R14 structure): encproj | rankF | s3off |
// targetproj | rankF | s3off | target2.
// This round: rank chunks 256->128 (2048 blocks, half serial work/block);
// targetproj 512->1024 blocks (4 rows/block via proj4_dev).
// e[t,s,h]=lrelu(dst_t+src_s) factors per branch around -dst.

#define N 4096
#define D 64
#define H 4
#define HD 256
#define TS 66

#define AS(p, v) __hip_atomic_store((p), (v), __ATOMIC_RELAXED, __HIP_MEMORY_SCOPE_AGENT)
#define AL(p)    __hip_atomic_load((p), __ATOMIC_RELAXED, __HIP_MEMORY_SCOPE_AGENT)

__device__ __forceinline__ void fma4(float4& a, float s, const float4& b) {
  a.x = fmaf(s, b.x, a.x); a.y = fmaf(s, b.y, a.y);
  a.z = fmaf(s, b.z, a.z); a.w = fmaf(s, b.w, a.w);
}

// ---- proj (8 rows/block, 2 rows/thread): used by encproj ----
__device__ __forceinline__ void proj_dev(const float (*xs)[64], int r0,
    const float* __restrict__ W, const float* __restrict__ asrc,
    const float* __restrict__ adst, float* __restrict__ h2,
    float* __restrict__ ssrc, float* __restrict__ sdst) {
  int tid = threadIdx.x;
  int lane6 = tid & 63;
  int c0 = lane6 * 4;
  int hh = lane6 >> 4;
  int rbase = (tid >> 6) * 2;
  float4 acc0 = make_float4(0.f, 0.f, 0.f, 0.f);
  float4 acc1 = make_float4(0.f, 0.f, 0.f, 0.f);
#pragma unroll
  for (int kq = 0; kq < 16; ++kq) {
    const float* Wk = W + kq * 4 * 256 + c0;
    float4 w0 = *(const float4*)(Wk);
    float4 w1 = *(const float4*)(Wk + 256);
    float4 w2 = *(const float4*)(Wk + 512);
    float4 w3 = *(const float4*)(Wk + 768);
    float4 x0 = *(const float4*)(&xs[rbase][kq * 4]);
    float4 x1 = *(const float4*)(&xs[rbase + 1][kq * 4]);
    fma4(acc0, x0.x, w0); fma4(acc0, x0.y, w1); fma4(acc0, x0.z, w2); fma4(acc0, x0.w, w3);
    fma4(acc1, x1.x, w0); fma4(acc1, x1.y, w1); fma4(acc1, x1.z, w2); fma4(acc1, x1.w, w3);
  }
  float4 av = *(const float4*)(asrc + c0);
  float4 bv = *(const float4*)(adst + c0);
#pragma unroll
  for (int r = 0; r < 2; ++r) {
    float4 a = (r == 0) ? acc0 : acc1;
    int row = r0 + rbase + r;
    *(float4*)(h2 + row * 256 + c0) = a;
    float ps = a.x * av.x + a.y * av.y + a.z * av.z + a.w * av.w;
    float pd = a.x * bv.x + a.y * bv.y + a.z * bv.z + a.w * bv.w;
#pragma unroll
    for (int off = 8; off > 0; off >>= 1) {
      ps += __shfl_down(ps, off);
      pd += __shfl_down(pd, off);
    }
    if ((lane6 & 15) == 0) {
      ssrc[hh * N + row] = ps;
      sdst[hh * N + row] = pd;
    }
  }
}

// ---- proj4 (4 rows/block, 1 row/thread): used by targetproj ----
__device__ __forceinline__ void proj4_dev(const float (*xs)[64], int r0,
    const float* __restrict__ W, const float* __restrict__ asrc,
    const float* __restrict__ adst, float* __restrict__ h2,
    float* __restrict__ ssrc, float* __restrict__ sdst) {
  int tid = threadIdx.x;
  int lane6 = tid & 63;
  int c0 = lane6 * 4;
  int hh = lane6 >> 4;
  int w = tid >> 6;                 // wave = row
  float4 acc = make_float4(0.f, 0.f, 0.f, 0.f);
#pragma unroll
  for (int kq = 0; kq < 16; ++kq) {
    const float* Wk = W + kq * 4 * 256 + c0;
    float4 w0 = *(const float4*)(Wk);
    float4 w1 = *(const float4*)(Wk + 256);
    float4 w2 = *(const float4*)(Wk + 512);
    float4 w3 = *(const float4*)(Wk + 768);
    float4 x0 = *(const float4*)(&xs[w][kq * 4]);
    fma4(acc, x0.x, w0); fma4(acc, x0.y, w1); fma4(acc, x0.z, w2); fma4(acc, x0.w, w3);
  }
  float4 av = *(const float4*)(asrc + c0);
  float4 bv = *(const float4*)(adst + c0);
  int row = r0 + w;
  *(float4*)(h2 + row * 256 + c0) = acc;
  float ps = acc.x * av.x + acc.y * av.y + acc.z * av.z + acc.w * av.w;
  float pd = acc.x * bv.x + acc.y * bv.y + acc.z * bv.z + acc.w * bv.w;
#pragma unroll
  for (int off = 8; off > 0; off >>= 1) {
    ps += __shfl_down(ps, off);
    pd += __shfl_down(pd, off);
  }
  if ((lane6 & 15) == 0) {
    ssrc[hh * N + row] = ps;
    sdst[hh * N + row] = pd;
  }
}

// ---- layer1: encoder fused with proj; x staged coalesced ----
__global__ __launch_bounds__(256) void k_encproj(const float* __restrict__ x,
    const float* __restrict__ Wenc, const float* __restrict__ benc,
    const float* __restrict__ W, const float* __restrict__ asrc,
    const float* __restrict__ adst, float* __restrict__ h2,
    float* __restrict__ ssrc, float* __restrict__ sdst,
    int* __restrict__ sync) {
  __shared__ float xin[8][64];
  __shared__ float xs[8][64];
  int tid = threadIdx.x;
  int r0 = blockIdx.x * 8;
  if (blockIdx.x == 0 && tid < 136) sync[tid] = 0;
  if (tid < 128) ((float4*)xin)[tid] = ((const float4*)(x + r0 * 64))[tid];
  __syncthreads();
  {
    int row = tid >> 5, c = (tid & 31) * 2;
    float a0 = benc[c], a1 = benc[c + 1];
#pragma unroll
    for (int k = 0; k < 64; ++k) {
      float xv = xin[row][k];
      float2 w = *(const float2*)(Wenc + k * 64 + c);
      a0 = fmaf(xv, w.x, a0);
      a1 = fmaf(xv, w.y, a1);
    }
    xs[row][c] = fmaxf(a0, 0.f);
    xs[row][c + 1] = fmaxf(a1, 0.f);
  }
  __syncthreads();
  proj_dev(xs, r0, W, asrc, adst, h2, ssrc, sdst);
}

// ---- rank fused: 128-j chunks (grid (64,32)); last block reduces ----
__global__ __launch_bounds__(256) void k_rank_f(const float* __restrict__ ssrc,
    int* __restrict__ rpart, int* __restrict__ cnt,
    float* __restrict__ srtv, int* __restrict__ srti) {
  __shared__ __align__(16) float vs[128];
  __shared__ int lastflag;
  int h = blockIdx.x >> 4, ig = blockIdx.x & 15, c = blockIdx.y;
  int tid = threadIdx.x;
  if (tid < 128) vs[tid] = ssrc[h * N + c * 128 + tid];
  __syncthreads();
  int i = ig * 256 + tid;
  float vi = ssrc[h * N + i];
  int jbase = c * 128;
  int rank = 0;
  const float4* vs4 = (const float4*)vs;
#pragma unroll 4
  for (int j4 = 0; j4 < 32; ++j4) {
    float4 q = vs4[j4];
    int jb = jbase + (j4 << 2);
    rank += (q.x < vi || (q.x == vi && jb < i));
    rank += (q.y < vi || (q.y == vi && jb + 1 < i));
    rank += (q.z < vi || (q.z == vi && jb + 2 < i));
    rank += (q.w < vi || (q.w == vi && jb + 3 < i));
  }
  AS(&rpart[(c * H + h) * N + i], rank);
  asm volatile("s_waitcnt vmcnt(0)" ::: "memory");
  __syncthreads();
  if (tid == 0) {
    int prev = __hip_atomic_fetch_add(&cnt[h * 16 + ig], 1,
                 __ATOMIC_RELAXED, __HIP_MEMORY_SCOPE_AGENT);
    lastflag = (prev == 31);
  }
  __syncthreads();
  if (lastflag) {
    int rk = 0;
#pragma unroll
    for (int cc = 0; cc < 32; ++cc) rk += AL(&rpart[(cc * H + h) * N + i]);
    srtv[h * N + rk] = vi;
    srti[h * N + rk] = i;
  }
}

// ---- s3off: chunk-LOCAL tables; last block/head: SufT/PreT + bndG ----
__global__ __launch_bounds__(512) void k_s3off(const float* __restrict__ h2,
    const int* __restrict__ srti, const float* __restrict__ srtv,
    float* __restrict__ TA, float* __restrict__ TB, int* __restrict__ cnt,
    float* __restrict__ SA, float* __restrict__ PB,
    float* __restrict__ SufT, float* __restrict__ PreT,
    float* __restrict__ bndG) {
  __shared__ int pj[64];
  __shared__ float wa[64], wb[64];
  __shared__ float vt[64][66];
  __shared__ float segA[8][66], segB[8][66];
  __shared__ int lastflag;
  int h = blockIdx.x >> 6, c = blockIdx.x & 63;
  int tid = threadIdx.x, w = tid >> 6, lane = tid & 63;
  int j0 = c * 64;
  if (tid < 64) {
    int j = j0 + tid;
    pj[tid] = srti[h * N + j];
    float sv = srtv[h * N + j];
    float m1 = srtv[h * N + N - 1];
    wa[tid] = expf(sv - m1);
    wb[tid] = expf(0.2f * (sv - m1));
  }
  __syncthreads();
#pragma unroll
  for (int jj = 0; jj < 8; ++jj) {
    int j = jj * 8 + w;
    vt[j][lane] = h2[pj[j] * HD + h * 64 + lane];
  }
  __syncthreads();
  {
    float sA = 0.f, sB = 0.f;
#pragma unroll
    for (int jj = 0; jj < 8; ++jj) {
      int j = w * 8 + jj;
      float v = vt[j][lane];
      sA = fmaf(wa[j], v, sA);
      sB = fmaf(wb[j], v, sB);
    }
    segA[w][lane] = sA; segB[w][lane] = sB;
    if (lane == 0) {
      float swA = 0.f, swB = 0.f;
#pragma unroll
      for (int jj = 0; jj < 8; ++jj) { swA += wa[w * 8 + jj]; swB += wb[w * 8 + jj]; }
      segA[w][64] = swA; segB[w][64] = swB;
    }
  }
  __syncthreads();
  size_t base = (size_t)h * (N + 1);
  {
    float acc = 0.f;
    for (int w2 = w + 1; w2 < 8; ++w2) acc += segA[w2][lane];
#pragma unroll
    for (int jj = 7; jj >= 0; --jj) {
      int j = w * 8 + jj;
      acc = fmaf(wa[j], vt[j][lane], acc);
      SA[(base + j0 + j) * TS + lane] = acc;
    }
  }
  {
    float acc = 0.f;
    for (int w2 = 0; w2 < w; ++w2) acc += segB[w2][lane];
#pragma unroll
    for (int jj = 0; jj < 8; ++jj) {
      int j = w * 8 + jj;
      PB[(base + j0 + j) * TS + lane] = acc;
      acc = fmaf(wb[j], vt[j][lane], acc);
    }
  }
  if (lane == 0) {
    float a = 0.f;
    for (int w2 = w + 1; w2 < 8; ++w2) a += segA[w2][64];
#pragma unroll
    for (int jj = 7; jj >= 0; --jj) {
      int j = w * 8 + jj;
      a += wa[j];
      SA[(base + j0 + j) * TS + 64] = a;
    }
  }
  if (lane == 1) {
    float bsum = 0.f;
    for (int w2 = 0; w2 < w; ++w2) bsum += segB[w2][64];
#pragma unroll
    for (int jj = 0; jj < 8; ++jj) {
      int j = w * 8 + jj;
      PB[(base + j0 + j) * TS + 64] = bsum;
      bsum += wb[j];
    }
  }
  if (tid < 65) {
    float tA = 0.f, tB = 0.f;
#pragma unroll
    for (int w2 = 0; w2 < 8; ++w2) { tA += segA[w2][tid]; tB += segB[w2][tid]; }
    AS(&TA[(h * 64 + c) * TS + tid], tA);
    AS(&TB[(h * 64 + c) * TS + tid], tB);
  }
  asm volatile("s_waitcnt vmcnt(0)" ::: "memory");
  __syncthreads();
  if (tid == 0) {
    int prev = __hip_atomic_fetch_add(&cnt[h], 1,
                 __ATOMIC_RELAXED, __HIP_MEMORY_SCOPE_AGENT);
    lastflag = (prev == 63);
  }
  __syncthreads();
  if (!lastflag) return;
  __syncthreads();
  if (tid < 64) bndG[h * 64 + tid] = srtv[h * N + tid * 64];
#pragma unroll
  for (int it = 0; it < 9; ++it) {
    int idx = it * 512 + tid;
    if (idx < 64 * 65) {
      int cc = idx / 65, col = idx - cc * 65;
      vt[cc][col] = AL(&TA[(h * 64 + cc) * TS + col]);
    }
  }
  __syncthreads();
  if (tid < 65) {
    float acc = 0.f;
    SufT[(h * 65 + 64) * TS + tid] = 0.f;
    for (int cc = 63; cc >= 0; --cc) {
      SufT[(h * 65 + cc) * TS + tid] = acc;
      acc += vt[cc][tid];
    }
  }
  __syncthreads();
#pragma unroll
  for (int it = 0; it < 9; ++it) {
    int idx = it * 512 + tid;
    if (idx < 64 * 65) {
      int cc = idx / 65, col = idx - cc * 65;
      vt[cc][col] = AL(&TB[(h * 64 + cc) * TS + col]);
    }
  }
  __syncthreads();
  if (tid < 65) {
    float acc = 0.f;
    for (int cc = 0; cc < 64; ++cc) {
      PreT[(h * 65 + cc) * TS + tid] = acc;
      acc += vt[cc][tid];
    }
    PreT[(h * 65 + 64) * TS + tid] = acc;
    SA[(base + N) * TS + tid] = 0.f;
    PB[(base + N) * TS + tid] = 0.f;
  }
}

// ---- target core: ntask groups of 4 rows; local tables + Suf/Pre ----
template <int MODE>
__device__ __forceinline__ void target_dev(int t0, int tid,
    const float* __restrict__ sdst, const float* __restrict__ srtv,
    const float* __restrict__ SA, const float* __restrict__ PB,
    const float* __restrict__ SufT, const float* __restrict__ PreT,
    const float* __restrict__ bias, float (*xsout)[64], const float (*bnd)[64],
    const float* __restrict__ Wact, const float* __restrict__ bact,
    const float* __restrict__ Wcri, const float* __restrict__ bcri,
    float* __restrict__ out, int ntask) {
  int lane = tid & 63;
  for (int task = 0; task < ntask; ++task) {
    int r = task * 4 + (tid >> 6);
    int t = t0 + r;
    float acc = 0.f;
#pragma unroll
    for (int h = 0; h < H; ++h) {
      const float* sv = srtv + h * N;
      float dst = sdst[h * N + t];
      float thr = -dst;
      float m1 = sv[N - 1];
      unsigned long long b1m = __ballot(bnd[h][lane] <= thr);
      int c1 = __popcll(b1m);
      int seg = c1 > 0 ? c1 - 1 : 0;
      unsigned long long b2m = __ballot(sv[seg * 64 + lane] <= thr);
      int k = seg * 64 + __popcll(b2m);
      int c = k >> 6;
      float u = dst + m1;
      float g = fmaxf(u, 0.2f * u);
      float wAt = expf(u - g);
      float wBt = expf(0.2f * u - g);
      const float* sa = SA + (size_t)(h * (N + 1) + k) * TS;
      const float* pb = PB + (size_t)(h * (N + 1) + k) * TS;
      const float* sf = SufT + (size_t)(h * 65 + c) * TS;
      const float* pr = PreT + (size_t)(h * 65 + c) * TS;
      float num = wAt * (sa[lane] + sf[lane]) + wBt * (pb[lane] + pr[lane]);
      float den = wAt * (sa[64] + sf[64]) + wBt * (pb[64] + pr[64]);
      acc += num / den;
    }
    float hv = fmaxf(acc * 0.25f + bias[lane], 0.f);
    if constexpr (MODE == 0) {
      xsout[r][lane] = hv;
    } else {
      float p0 = hv * Wact[lane * 2 + 0];
      float p1 = hv * Wact[lane * 2 + 1];
      float p2 = hv * Wcri[lane];
#pragma unroll
      for (int off = 32; off > 0; off >>= 1) {
        p0 += __shfl_down(p0, off);
        p1 += __shfl_down(p1, off);
        p2 += __shfl_down(p2, off);
      }
      if (lane == 0) {
        float l0 = fminf(fmaxf(p0 + bact[0], -5.f), 5.f);
        float l1 = fminf(fmaxf(p1 + bact[1], -5.f), 5.f);
        out[t * 2 + 0] = l0;
        out[t * 2 + 1] = fabsf(l1);
        out[2 * N + t] = p2 + bcri[0];
      }
    }
  }
}

// ---- target1 (4 rows -> LDS) fused with proj2 (proj4), 1024 blocks ----
__global__ __launch_bounds__(256) void k_targetproj(
    const float* __restrict__ sdst, const float* __restrict__ srtv,
    const float* __restrict__ SA, const float* __restrict__ PB,
    const float* __restrict__ SufT, const float* __restrict__ PreT,
    const float* __restrict__ bndG, const float* __restrict__ bias,
    const float* __restrict__ W, const float* __restrict__ asrc,
    const float* __restrict__ adst, float* __restrict__ h2,
    float* __restrict__ ssrc2, float* __restrict__ sdst2) {
  __shared__ float xs[4][64];
  __shared__ float bnd[4][64];
  int tid = threadIdx.x;
  int r0 = blockIdx.x * 4;
  ((float*)bnd)[tid] = bndG[tid];
  __syncthreads();
  target_dev<0>(r0, tid, sdst, srtv, SA, PB, SufT, PreT, bias, xs, bnd,
                nullptr, nullptr, nullptr, nullptr, nullptr, 1);
  __syncthreads();
  proj4_dev(xs, r0, W, asrc, adst, h2, ssrc2, sdst2);
}

// ---- target2 + heads ----
__global__ __launch_bounds__(256) void k_target2(
    const float* __restrict__ sdst, const float* __restrict__ srtv,
    const float* __restrict__ SA, const float* __restrict__ PB,
    const float* __restrict__ SufT, const float* __restrict__ PreT,
    const float* __restrict__ bndG, const float* __restrict__ bias,
    const float* __restrict__ Wact, const float* __restrict__ bact,
    const float* __restrict__ Wcri, const float* __restrict__ bcri,
    float* __restrict__ out) {
  __shared__ float bnd[4][64];
  int tid = threadIdx.x;
  ((float*)bnd)[tid] = bndG[tid];
  __syncthreads();
  target_dev<1>(blockIdx.x * 4, tid, sdst, srtv, SA, PB, SufT, PreT, bias,
                nullptr, bnd, Wact, bact, Wcri, bcri, out, 1);
}

extern "C" void kernel_launch(void* const* d_in, const int* in_sizes, int n_in,
                              void* d_out, int out_size, void* d_ws, size_t ws_size,
                              hipStream_t stream) {
    (void)in_sizes; (void)n_in; (void)out_size; (void)ws_size;
    const float* x     = (const float*)d_in[0];
    const float* W_enc = (const float*)d_in[1];
    const float* b_enc = (const float*)d_in[2];
    const float* W1    = (const float*)d_in[3];
    const float* as1   = (const float*)d_in[4];
    const float* ad1   = (const float*)d_in[5];
    const float* b1    = (const float*)d_in[6];
    const float* W2    = (const float*)d_in[7];
    const float* as2   = (const float*)d_in[8];
    const float* ad2   = (const float*)d_in[9];
    const float* b2    = (const float*)d_in[10];
    const float* W_act = (const float*)d_in[11];
    const float* b_act = (const float*)d_in[12];
    const float* W_cri = (const float*)d_in[13];
    const float* b_cri = (const float*)d_in[14];
    float* out = (float*)d_out;

    float* p = (float*)d_ws;
    float* h2    = p; p += N * HD;
    float* ssrc1 = p; p += H * N;
    float* sdst1 = p; p += H * N;
    float* ssrc2 = p; p += H * N;
    float* sdst2 = p; p += H * N;
    float* srtv  = p; p += H * N;
    int*   srti  = (int*)p; p += H * N;
    float* TA    = p; p += H * 64 * TS;
    float* TB    = p; p += H * 64 * TS;
    float* SufT  = p; p += H * 65 * TS;
    float* PreT  = p; p += H * 65 * TS;
    float* bndG  = p; p += H * 64;
    float* SA    = p; p += (size_t)H * (N + 1) * TS;
    float* PB    = p; p += (size_t)H * (N + 1) * TS;
    int*   rpart = (int*)p; p += 32 * H * N;
    int*   sync  = (int*)p; p += 256;

    int* rcnt1 = sync;
    int* scnt1 = sync + 64;
    int* rcnt2 = sync + 68;
    int* scnt2 = sync + 132;

    dim3 rgrid(64, 32);

    // layer 1
    k_encproj<<<N / 8, 256, 0, stream>>>(x, W_enc, b_enc, W1, as1, ad1,
                                         h2, ssrc1, sdst1, sync);
    k_rank_f<<<rgrid, 256, 0, stream>>>(ssrc1, rpart, rcnt1, srtv, srti);
    k_s3off<<<256, 512, 0, stream>>>(h2, srti, srtv, TA, TB, scnt1, SA, PB,
                                     SufT, PreT, bndG);
    k_targetproj<<<N / 4, 256, 0, stream>>>(sdst1, srtv, SA, PB, SufT, PreT,
                                            bndG, b1, W2, as2, ad2, h2, ssrc2, sdst2);
    // layer 2
    k_rank_f<<<rgrid, 256, 0, stream>>>(ssrc2, rpart, rcnt2, srtv, srti);
    k_s3off<<<256, 512, 0, stream>>>(h2, srti, srtv, TA, TB, scnt2, SA, PB,
                                     SufT, PreT, bndG);
    k_target2<<<N / 4, 256, 0, stream>>>(sdst2, srtv, SA, PB, SufT, PreT,
                                         bndG, b2, W_act, b_act, W_cri, b_cri, out);
}

// Round 19
// 94.098 us; speedup vs baseline: 1.2580x; 1.0429x over previous
//
#include <hip/hip_runtime.h>

// GAT on fully-connected graph, N=4096, F=D=64, H=4, OUT=2.
// 7 fence-free dispatches (R14 structure): encproj | rankF | s3off |
// targetproj | rankF | s3off | target2.
// R18: rank 128-j chunks (2048 blocks); targetproj 1024 blocks (proj4).
// R19: encproj also 1024 blocks / 4 rows (encoder 1 col/thread + proj4).
// e[t,s,h]=lrelu(dst_t+src_s) factors per branch around -dst.

#define N 4096
#define D 64
#define H 4
#define HD 256
#define TS 66

#define AS(p, v) __hip_atomic_store((p), (v), __ATOMIC_RELAXED, __HIP_MEMORY_SCOPE_AGENT)
#define AL(p)    __hip_atomic_load((p), __ATOMIC_RELAXED, __HIP_MEMORY_SCOPE_AGENT)

__device__ __forceinline__ void fma4(float4& a, float s, const float4& b) {
  a.x = fmaf(s, b.x, a.x); a.y = fmaf(s, b.y, a.y);
  a.z = fmaf(s, b.z, a.z); a.w = fmaf(s, b.w, a.w);
}

// ---- proj4 (4 rows/block, 1 row/thread-wave): shared by encproj/targetproj ----
__device__ __forceinline__ void proj4_dev(const float (*xs)[64], int r0,
    const float* __restrict__ W, const float* __restrict__ asrc,
    const float* __restrict__ adst, float* __restrict__ h2,
    float* __restrict__ ssrc, float* __restrict__ sdst) {
  int tid = threadIdx.x;
  int lane6 = tid & 63;
  int c0 = lane6 * 4;
  int hh = lane6 >> 4;
  int w = tid >> 6;                 // wave = row
  float4 acc = make_float4(0.f, 0.f, 0.f, 0.f);
#pragma unroll
  for (int kq = 0; kq < 16; ++kq) {
    const float* Wk = W + kq * 4 * 256 + c0;
    float4 w0 = *(const float4*)(Wk);
    float4 w1 = *(const float4*)(Wk + 256);
    float4 w2 = *(const float4*)(Wk + 512);
    float4 w3 = *(const float4*)(Wk + 768);
    float4 x0 = *(const float4*)(&xs[w][kq * 4]);
    fma4(acc, x0.x, w0); fma4(acc, x0.y, w1); fma4(acc, x0.z, w2); fma4(acc, x0.w, w3);
  }
  float4 av = *(const float4*)(asrc + c0);
  float4 bv = *(const float4*)(adst + c0);
  int row = r0 + w;
  *(float4*)(h2 + row * 256 + c0) = acc;
  float ps = acc.x * av.x + acc.y * av.y + acc.z * av.z + acc.w * av.w;
  float pd = acc.x * bv.x + acc.y * bv.y + acc.z * bv.z + acc.w * bv.w;
#pragma unroll
  for (int off = 8; off > 0; off >>= 1) {
    ps += __shfl_down(ps, off);
    pd += __shfl_down(pd, off);
  }
  if ((lane6 & 15) == 0) {
    ssrc[hh * N + row] = ps;
    sdst[hh * N + row] = pd;
  }
}

// ---- layer1: encoder (4 rows, 1 col/thread) fused with proj4; 1024 blocks ----
__global__ __launch_bounds__(256) void k_encproj(const float* __restrict__ x,
    const float* __restrict__ Wenc, const float* __restrict__ benc,
    const float* __restrict__ W, const float* __restrict__ asrc,
    const float* __restrict__ adst, float* __restrict__ h2,
    float* __restrict__ ssrc, float* __restrict__ sdst,
    int* __restrict__ sync) {
  __shared__ float xin[4][64];
  __shared__ float xs[4][64];
  int tid = threadIdx.x;
  int r0 = blockIdx.x * 4;
  if (blockIdx.x == 0 && tid < 136) sync[tid] = 0;
  if (tid < 64) ((float4*)xin)[tid] = ((const float4*)(x + r0 * 64))[tid];
  __syncthreads();
  {
    int row = tid >> 6, c = tid & 63;
    float a0 = benc[c];
#pragma unroll
    for (int k = 0; k < 64; ++k)
      a0 = fmaf(xin[row][k], Wenc[k * 64 + c], a0);
    xs[row][c] = fmaxf(a0, 0.f);
  }
  __syncthreads();
  proj4_dev(xs, r0, W, asrc, adst, h2, ssrc, sdst);
}

// ---- rank fused: 128-j chunks (grid (64,32)); last block reduces ----
__global__ __launch_bounds__(256) void k_rank_f(const float* __restrict__ ssrc,
    int* __restrict__ rpart, int* __restrict__ cnt,
    float* __restrict__ srtv, int* __restrict__ srti) {
  __shared__ __align__(16) float vs[128];
  __shared__ int lastflag;
  int h = blockIdx.x >> 4, ig = blockIdx.x & 15, c = blockIdx.y;
  int tid = threadIdx.x;
  if (tid < 128) vs[tid] = ssrc[h * N + c * 128 + tid];
  __syncthreads();
  int i = ig * 256 + tid;
  float vi = ssrc[h * N + i];
  int jbase = c * 128;
  int rank = 0;
  const float4* vs4 = (const float4*)vs;
#pragma unroll 4
  for (int j4 = 0; j4 < 32; ++j4) {
    float4 q = vs4[j4];
    int jb = jbase + (j4 << 2);
    rank += (q.x < vi || (q.x == vi && jb < i));
    rank += (q.y < vi || (q.y == vi && jb + 1 < i));
    rank += (q.z < vi || (q.z == vi && jb + 2 < i));
    rank += (q.w < vi || (q.w == vi && jb + 3 < i));
  }
  AS(&rpart[(c * H + h) * N + i], rank);
  asm volatile("s_waitcnt vmcnt(0)" ::: "memory");
  __syncthreads();
  if (tid == 0) {
    int prev = __hip_atomic_fetch_add(&cnt[h * 16 + ig], 1,
                 __ATOMIC_RELAXED, __HIP_MEMORY_SCOPE_AGENT);
    lastflag = (prev == 31);
  }
  __syncthreads();
  if (lastflag) {
    int rk = 0;
#pragma unroll
    for (int cc = 0; cc < 32; ++cc) rk += AL(&rpart[(cc * H + h) * N + i]);
    srtv[h * N + rk] = vi;
    srti[h * N + rk] = i;
  }
}

// ---- s3off: chunk-LOCAL tables; last block/head: SufT/PreT + bndG ----
__global__ __launch_bounds__(512) void k_s3off(const float* __restrict__ h2,
    const int* __restrict__ srti, const float* __restrict__ srtv,
    float* __restrict__ TA, float* __restrict__ TB, int* __restrict__ cnt,
    float* __restrict__ SA, float* __restrict__ PB,
    float* __restrict__ SufT, float* __restrict__ PreT,
    float* __restrict__ bndG) {
  __shared__ int pj[64];
  __shared__ float wa[64], wb[64];
  __shared__ float vt[64][66];
  __shared__ float segA[8][66], segB[8][66];
  __shared__ int lastflag;
  int h = blockIdx.x >> 6, c = blockIdx.x & 63;
  int tid = threadIdx.x, w = tid >> 6, lane = tid & 63;
  int j0 = c * 64;
  if (tid < 64) {
    int j = j0 + tid;
    pj[tid] = srti[h * N + j];
    float sv = srtv[h * N + j];
    float m1 = srtv[h * N + N - 1];
    wa[tid] = expf(sv - m1);
    wb[tid] = expf(0.2f * (sv - m1));
  }
  __syncthreads();
#pragma unroll
  for (int jj = 0; jj < 8; ++jj) {
    int j = jj * 8 + w;
    vt[j][lane] = h2[pj[j] * HD + h * 64 + lane];
  }
  __syncthreads();
  {
    float sA = 0.f, sB = 0.f;
#pragma unroll
    for (int jj = 0; jj < 8; ++jj) {
      int j = w * 8 + jj;
      float v = vt[j][lane];
      sA = fmaf(wa[j], v, sA);
      sB = fmaf(wb[j], v, sB);
    }
    segA[w][lane] = sA; segB[w][lane] = sB;
    if (lane == 0) {
      float swA = 0.f, swB = 0.f;
#pragma unroll
      for (int jj = 0; jj < 8; ++jj) { swA += wa[w * 8 + jj]; swB += wb[w * 8 + jj]; }
      segA[w][64] = swA; segB[w][64] = swB;
    }
  }
  __syncthreads();
  size_t base = (size_t)h * (N + 1);
  {
    float acc = 0.f;
    for (int w2 = w + 1; w2 < 8; ++w2) acc += segA[w2][lane];
#pragma unroll
    for (int jj = 7; jj >= 0; --jj) {
      int j = w * 8 + jj;
      acc = fmaf(wa[j], vt[j][lane], acc);
      SA[(base + j0 + j) * TS + lane] = acc;
    }
  }
  {
    float acc = 0.f;
    for (int w2 = 0; w2 < w; ++w2) acc += segB[w2][lane];
#pragma unroll
    for (int jj = 0; jj < 8; ++jj) {
      int j = w * 8 + jj;
      PB[(base + j0 + j) * TS + lane] = acc;
      acc = fmaf(wb[j], vt[j][lane], acc);
    }
  }
  if (lane == 0) {
    float a = 0.f;
    for (int w2 = w + 1; w2 < 8; ++w2) a += segA[w2][64];
#pragma unroll
    for (int jj = 7; jj >= 0; --jj) {
      int j = w * 8 + jj;
      a += wa[j];
      SA[(base + j0 + j) * TS + 64] = a;
    }
  }
  if (lane == 1) {
    float bsum = 0.f;
    for (int w2 = 0; w2 < w; ++w2) bsum += segB[w2][64];
#pragma unroll
    for (int jj = 0; jj < 8; ++jj) {
      int j = w * 8 + jj;
      PB[(base + j0 + j) * TS + 64] = bsum;
      bsum += wb[j];
    }
  }
  if (tid < 65) {
    float tA = 0.f, tB = 0.f;
#pragma unroll
    for (int w2 = 0; w2 < 8; ++w2) { tA += segA[w2][tid]; tB += segB[w2][tid]; }
    AS(&TA[(h * 64 + c) * TS + tid], tA);
    AS(&TB[(h * 64 + c) * TS + tid], tB);
  }
  asm volatile("s_waitcnt vmcnt(0)" ::: "memory");
  __syncthreads();
  if (tid == 0) {
    int prev = __hip_atomic_fetch_add(&cnt[h], 1,
                 __ATOMIC_RELAXED, __HIP_MEMORY_SCOPE_AGENT);
    lastflag = (prev == 63);
  }
  __syncthreads();
  if (!lastflag) return;
  __syncthreads();
  if (tid < 64) bndG[h * 64 + tid] = srtv[h * N + tid * 64];
#pragma unroll
  for (int it = 0; it < 9; ++it) {
    int idx = it * 512 + tid;
    if (idx < 64 * 65) {
      int cc = idx / 65, col = idx - cc * 65;
      vt[cc][col] = AL(&TA[(h * 64 + cc) * TS + col]);
    }
  }
  __syncthreads();
  if (tid < 65) {
    float acc = 0.f;
    SufT[(h * 65 + 64) * TS + tid] = 0.f;
    for (int cc = 63; cc >= 0; --cc) {
      SufT[(h * 65 + cc) * TS + tid] = acc;
      acc += vt[cc][tid];
    }
  }
  __syncthreads();
#pragma unroll
  for (int it = 0; it < 9; ++it) {
    int idx = it * 512 + tid;
    if (idx < 64 * 65) {
      int cc = idx / 65, col = idx - cc * 65;
      vt[cc][col] = AL(&TB[(h * 64 + cc) * TS + col]);
    }
  }
  __syncthreads();
  if (tid < 65) {
    float acc = 0.f;
    for (int cc = 0; cc < 64; ++cc) {
      PreT[(h * 65 + cc) * TS + tid] = acc;
      acc += vt[cc][tid];
    }
    PreT[(h * 65 + 64) * TS + tid] = acc;
    SA[(base + N) * TS + tid] = 0.f;
    PB[(base + N) * TS + tid] = 0.f;
  }
}

// ---- target core: 4 rows; local tables + Suf/Pre ----
template <int MODE>
__device__ __forceinline__ void target_dev(int t0, int tid,
    const float* __restrict__ sdst, const float* __restrict__ srtv,
    const float* __restrict__ SA, const float* __restrict__ PB,
    const float* __restrict__ SufT, const float* __restrict__ PreT,
    const float* __restrict__ bias, float (*xsout)[64], const float (*bnd)[64],
    const float* __restrict__ Wact, const float* __restrict__ bact,
    const float* __restrict__ Wcri, const float* __restrict__ bcri,
    float* __restrict__ out) {
  int lane = tid & 63;
  int r = tid >> 6;
  int t = t0 + r;
  float acc = 0.f;
#pragma unroll
  for (int h = 0; h < H; ++h) {
    const float* sv = srtv + h * N;
    float dst = sdst[h * N + t];
    float thr = -dst;
    float m1 = sv[N - 1];
    unsigned long long b1m = __ballot(bnd[h][lane] <= thr);
    int c1 = __popcll(b1m);
    int seg = c1 > 0 ? c1 - 1 : 0;
    unsigned long long b2m = __ballot(sv[seg * 64 + lane] <= thr);
    int k = seg * 64 + __popcll(b2m);
    int c = k >> 6;
    float u = dst + m1;
    float g = fmaxf(u, 0.2f * u);
    float wAt = expf(u - g);
    float wBt = expf(0.2f * u - g);
    const float* sa = SA + (size_t)(h * (N + 1) + k) * TS;
    const float* pb = PB + (size_t)(h * (N + 1) + k) * TS;
    const float* sf = SufT + (size_t)(h * 65 + c) * TS;
    const float* pr = PreT + (size_t)(h * 65 + c) * TS;
    float num = wAt * (sa[lane] + sf[lane]) + wBt * (pb[lane] + pr[lane]);
    float den = wAt * (sa[64] + sf[64]) + wBt * (pb[64] + pr[64]);
    acc += num / den;
  }
  float hv = fmaxf(acc * 0.25f + bias[lane], 0.f);
  if constexpr (MODE == 0) {
    xsout[r][lane] = hv;
  } else {
    float p0 = hv * Wact[lane * 2 + 0];
    float p1 = hv * Wact[lane * 2 + 1];
    float p2 = hv * Wcri[lane];
#pragma unroll
    for (int off = 32; off > 0; off >>= 1) {
      p0 += __shfl_down(p0, off);
      p1 += __shfl_down(p1, off);
      p2 += __shfl_down(p2, off);
    }
    if (lane == 0) {
      float l0 = fminf(fmaxf(p0 + bact[0], -5.f), 5.f);
      float l1 = fminf(fmaxf(p1 + bact[1], -5.f), 5.f);
      out[t * 2 + 0] = l0;
      out[t * 2 + 1] = fabsf(l1);
      out[2 * N + t] = p2 + bcri[0];
    }
  }
}

// ---- target1 (4 rows -> LDS) fused with proj2 (proj4), 1024 blocks ----
__global__ __launch_bounds__(256) void k_targetproj(
    const float* __restrict__ sdst, const float* __restrict__ srtv,
    const float* __restrict__ SA, const float* __restrict__ PB,
    const float* __restrict__ SufT, const float* __restrict__ PreT,
    const float* __restrict__ bndG, const float* __restrict__ bias,
    const float* __restrict__ W, const float* __restrict__ asrc,
    const float* __restrict__ adst, float* __restrict__ h2,
    float* __restrict__ ssrc2, float* __restrict__ sdst2) {
  __shared__ float xs[4][64];
  __shared__ float bnd[4][64];
  int tid = threadIdx.x;
  int r0 = blockIdx.x * 4;
  ((float*)bnd)[tid] = bndG[tid];
  __syncthreads();
  target_dev<0>(r0, tid, sdst, srtv, SA, PB, SufT, PreT, bias, xs, bnd,
                nullptr, nullptr, nullptr, nullptr, nullptr);
  __syncthreads();
  proj4_dev(xs, r0, W, asrc, adst, h2, ssrc2, sdst2);
}

// ---- target2 + heads ----
__global__ __launch_bounds__(256) void k_target2(
    const float* __restrict__ sdst, const float* __restrict__ srtv,
    const float* __restrict__ SA, const float* __restrict__ PB,
    const float* __restrict__ SufT, const float* __restrict__ PreT,
    const float* __restrict__ bndG, const float* __restrict__ bias,
    const float* __restrict__ Wact, const float* __restrict__ bact,
    const float* __restrict__ Wcri, const float* __restrict__ bcri,
    float* __restrict__ out) {
  __shared__ float bnd[4][64];
  int tid = threadIdx.x;
  ((float*)bnd)[tid] = bndG[tid];
  __syncthreads();
  target_dev<1>(blockIdx.x * 4, tid, sdst, srtv, SA, PB, SufT, PreT, bias,
                nullptr, bnd, Wact, bact, Wcri, bcri, out);
}

extern "C" void kernel_launch(void* const* d_in, const int* in_sizes, int n_in,
                              void* d_out, int out_size, void* d_ws, size_t ws_size,
                              hipStream_t stream) {
    (void)in_sizes; (void)n_in; (void)out_size; (void)ws_size;
    const float* x     = (const float*)d_in[0];
    const float* W_enc = (const float*)d_in[1];
    const float* b_enc = (const float*)d_in[2];
    const float* W1    = (const float*)d_in[3];
    const float* as1   = (const float*)d_in[4];
    const float* ad1   = (const float*)d_in[5];
    const float* b1    = (const float*)d_in[6];
    const float* W2    = (const float*)d_in[7];
    const float* as2   = (const float*)d_in[8];
    const float* ad2   = (const float*)d_in[9];
    const float* b2    = (const float*)d_in[10];
    const float* W_act = (const float*)d_in[11];
    const float* b_act = (const float*)d_in[12];
    const float* W_cri = (const float*)d_in[13];
    const float* b_cri = (const float*)d_in[14];
    float* out = (float*)d_out;

    float* p = (float*)d_ws;
    float* h2    = p; p += N * HD;
    float* ssrc1 = p; p += H * N;
    float* sdst1 = p; p += H * N;
    float* ssrc2 = p; p += H * N;
    float* sdst2 = p; p += H * N;
    float* srtv  = p; p += H * N;
    int*   srti  = (int*)p; p += H * N;
    float* TA    = p; p += H * 64 * TS;
    float* TB    = p; p += H * 64 * TS;
    float* SufT  = p; p += H * 65 * TS;
    float* PreT  = p; p += H * 65 * TS;
    float* bndG  = p; p += H * 64;
    float* SA    = p; p += (size_t)H * (N + 1) * TS;
    float* PB    = p; p += (size_t)H * (N + 1) * TS;
    int*   rpart = (int*)p; p += 32 * H * N;
    int*   sync  = (int*)p; p += 256;

    int* rcnt1 = sync;
    int* scnt1 = sync + 64;
    int* rcnt2 = sync + 68;
    int* scnt2 = sync + 132;

    dim3 rgrid(64, 32);

    // layer 1
    k_encproj<<<N / 4, 256, 0, stream>>>(x, W_enc, b_enc, W1, as1, ad1,
                                         h2, ssrc1, sdst1, sync);
    k_rank_f<<<rgrid, 256, 0, stream>>>(ssrc1, rpart, rcnt1, srtv, srti);
    k_s3off<<<256, 512, 0, stream>>>(h2, srti, srtv, TA, TB, scnt1, SA, PB,
                                     SufT, PreT, bndG);
    k_targetproj<<<N / 4, 256, 0, stream>>>(sdst1, srtv, SA, PB, SufT, PreT,
                                            bndG, b1, W2, as2, ad2, h2, ssrc2, sdst2);
    // layer 2
    k_rank_f<<<rgrid, 256, 0, stream>>>(ssrc2, rpart, rcnt2, srtv, srti);
    k_s3off<<<256, 512, 0, stream>>>(h2, srti, srtv, TA, TB, scnt2, SA, PB,
                                     SufT, PreT, bndG);
    k_target2<<<N / 4, 256, 0, stream>>>(sdst2, srtv, SA, PB, SufT, PreT,
                                         bndG, b2, W_act, b_act, W_cri, b_cri, out);
}